// Round 7
// baseline (511.008 us; speedup 1.0000x reference)
//
#include <hip/hip_runtime.h>

#define BEVW 432
#define BEVH 496
#define NCELL (BEVW*BEVH)      // 214272
#define NVOX  40000
#define EPSB  1e-5f

typedef float f32x2 __attribute__((ext_vector_type(2)));
typedef float f32x4 __attribute__((ext_vector_type(4)));
typedef unsigned int u32x4 __attribute__((ext_vector_type(4)));
typedef short bf16x8 __attribute__((ext_vector_type(8)));

// ---- repeat macros ----
#define REP8_0(M)  M(0) M(1) M(2) M(3) M(4) M(5) M(6) M(7)
#define REP8_8(M)  M(8) M(9) M(10) M(11) M(12) M(13) M(14) M(15)
#define REP16_0(M)  REP8_0(M)  REP8_8(M)

// ---------------- workspace layout (bytes) ----------------
// 0        : int nact (zeroed)
// 256      : int cnt[NCELL]  (zeroed)            -> 857344
// 857344   : int idx[NCELL]  (zeroed; aidx+1)    -> 1714432
// 1714432  : int list[NCELL*16]                  -> 15427840
// 15427840 : float voxelwise[NVOX*64]            -> 25667840
// 25667840 : int act[NVOX]                       -> 25827840
// 25827840 : float x17g[NVOX*128] (x19 lives here) -> 46307840
// 46307840 : float fold[1168]
// 46312512 : w4fh | 46320704: w4fl | 46328896: w3fh | 46337088: w3fl
// 46345280 : w2fh[1024] | 46347328 : w2fl[1024]

__device__ __forceinline__ float mishf(float y) {
    float e = __expf(fminf(y, 40.f));
    float n = e * (e + 2.f);
    return y * n * __builtin_amdgcn_rcpf(n + 2.f);
}

template <int CTRL>
__device__ __forceinline__ float dppmaxf(float a) {
    int p = __builtin_amdgcn_update_dpp(0, __float_as_int(a), CTRL, 0xF, 0xF, true);
    return fmaxf(a, __int_as_float(p));
}
#define WMAX32(a) { \
    a = dppmaxf<0xB1>(a); \
    a = dppmaxf<0x4E>(a); \
    a = dppmaxf<0x141>(a); \
    a = dppmaxf<0x140>(a); \
    a = fmaxf(a, __int_as_float(__builtin_amdgcn_ds_swizzle(__float_as_int(a), 0x401F))); }

__device__ __forceinline__ bf16x8 mkbf8(uint a, uint b, uint c, uint d) {
    u32x4 t = {a, b, c, d};
    return __builtin_bit_cast(bf16x8, t);
}

// split fp32 -> (hi bf16 | lo bf16 << 16). Hi = TRUNCATION (1 op); lo = x - hi is
// then exact in fp32, RNE'd to bf16. Combined representation err ~2^-17 rel.
__device__ __forceinline__ uint splitbf(float x) {
    uint rh = __float_as_uint(x) & 0xFFFF0000u;
    float lof = x - __uint_as_float(rh);
    uint ul = __float_as_uint(lof);
    uint rl = (ul + 0x7FFFu + ((ul >> 16) & 1u)) >> 16;
    return (rh >> 16) | (rl << 16);
}

// fold layout: vfe1 s@0 t@8 | vfe2 s@16 t@48 | vfe3 s@80 t@144 | vfe4 s@208 t@272
// bfe3 s@336 t@464 | bfe1 s@592 t@848 | bfe2 s@1104 t@1136
__global__ __launch_bounds__(256) void setup_kernel(
    const float* __restrict__ vbn1, const float* __restrict__ vbn2,
    const float* __restrict__ vbn3, const float* __restrict__ vbn4,
    const float* __restrict__ bbn1, const float* __restrict__ bbn2,
    const float* __restrict__ bbn3, const float* __restrict__ W4,
    const float* __restrict__ W3g, const float* __restrict__ W2g,
    float* __restrict__ fold, ushort* __restrict__ w4fh, ushort* __restrict__ w4fl,
    ushort* __restrict__ w3fh, ushort* __restrict__ w3fl,
    ushort* __restrict__ w2fh, ushort* __restrict__ w2fl)
{
    int tid = threadIdx.x;
    if (tid < 8)  { float s = vbn1[tid]/sqrtf(vbn1[24+tid]+EPSB);  fold[tid]      = s; fold[8+tid]   = vbn1[8+tid]  - vbn1[16+tid]*s; }
    if (tid < 32) { float s = vbn2[tid]/sqrtf(vbn2[96+tid]+EPSB);  fold[16+tid]   = s; fold[48+tid]  = vbn2[32+tid] - vbn2[64+tid]*s; }
    if (tid < 64) { float s = vbn3[tid]/sqrtf(vbn3[192+tid]+EPSB); fold[80+tid]   = s; fold[144+tid] = vbn3[64+tid] - vbn3[128+tid]*s; }
    if (tid < 64) { float s = vbn4[tid]/sqrtf(vbn4[192+tid]+EPSB); fold[208+tid]  = s; fold[272+tid] = vbn4[64+tid] - vbn4[128+tid]*s; }
    if (tid < 128){ float s = bbn3[tid]/sqrtf(bbn3[384+tid]+EPSB); fold[336+tid]  = s; fold[464+tid] = bbn3[128+tid]- bbn3[256+tid]*s; }
    { int g = tid >> 4, q = tid & 15;
      const float* b = bbn1 + g*64;
      float s = b[q]/sqrtf(b[48+q]+EPSB);
      fold[592+tid] = s; fold[848+tid] = b[16+q] - b[32+q]*s; }
    if (tid < 32) { int g = tid >> 1, c = tid & 1;
      const float* b = bbn2 + g*8;
      float s = b[c]/sqrtf(b[6+c]+EPSB);
      fold[1104+tid] = s; fold[1136+tid] = b[2+c] - b[4+c]*s; }

    // B-fragments (B[k][n] = W[n][k]) split bf16 hi/lo, for W4^T and W3^T (vfe).
    // frag idx = ((kc*4 + nt)*64 + lane)*8 + j ; n = (lane&15)+16nt ; k = kc*32 + (lane>>4)*8 + j
    for (int i = tid; i < 4096; i += 256) {
        int j = i & 7, ln = (i >> 3) & 63, nt = (i >> 9) & 3, kc = i >> 11;
        int n = (ln & 15) + nt*16;
        int k = kc*32 + (ln >> 4)*8 + j;
        {
            float val = W4[n*64 + k];
            uint u = splitbf(val);
            w4fh[i] = (ushort)(u & 0xFFFFu);
            w4fl[i] = (ushort)(u >> 16);
        }
        {
            float val = W3g[n*64 + k];
            uint u = splitbf(val);
            w3fh[i] = (ushort)(u & 0xFFFFu);
            w3fl[i] = (ushort)(u >> 16);
        }
    }

    // W2 B-fragments: K=16 padded to 32 with ZERO weights (k>=16 -> 0), N=32.
    for (int i = tid; i < 1024; i += 256) {
        int j = i & 7, ln = (i >> 3) & 63, nt = (i >> 9) & 1;
        int n = (ln & 15) + nt*16;
        int k = (ln >> 4)*8 + j;
        float val = (k < 16) ? W2g[n*16 + k] : 0.f;
        uint u = splitbf(val);
        w2fh[i] = (ushort)(u & 0xFFFFu);
        w2fl[i] = (ushort)(u >> 16);
    }
}

#define MF3(D, AH, AL, BH, BL) \
    D = __builtin_amdgcn_mfma_f32_16x16x32_bf16(AL, BH, D, 0, 0, 0); \
    D = __builtin_amdgcn_mfma_f32_16x16x32_bf16(AH, BL, D, 0, 0, 0); \
    D = __builtin_amdgcn_mfma_f32_16x16x32_bf16(AH, BH, D, 0, 0, 0);

// Load one A-tile (16 rows) from LDS rows (stride 33) and pack hi/lo bf16 frags.
#define LDA(SRCP, mt, AH, AL) { \
    const uint* ap_ = (SRCP) + ((lane & 15) + 16*(mt))*33 + quad*8; \
    uint u0 = ap_[0], u1 = ap_[1], u2 = ap_[2], u3 = ap_[3]; \
    uint u4 = ap_[4], u5 = ap_[5], u6 = ap_[6], u7 = ap_[7]; \
    AH = mkbf8(__builtin_amdgcn_perm(u1,u0,0x05040100), __builtin_amdgcn_perm(u3,u2,0x05040100), \
               __builtin_amdgcn_perm(u5,u4,0x05040100), __builtin_amdgcn_perm(u7,u6,0x05040100)); \
    AL = mkbf8(__builtin_amdgcn_perm(u1,u0,0x07060302), __builtin_amdgcn_perm(u3,u2,0x07060302), \
               __builtin_amdgcn_perm(u5,u4,0x07060302), __builtin_amdgcn_perm(u7,u6,0x07060302)); }

// fe2 A-tile: K=16 real data in cols 0-15. Quads 2,3 (k 16-31) RE-READ cols 0-15
// ((quad&1) addressing) so A stays finite; their B weights are exactly 0.
#define LDA2(SRCP, mt, AH, AL) { \
    const uint* ap_ = (SRCP) + ((lane & 15) + 16*(mt))*33 + (quad & 1)*8; \
    uint u0 = ap_[0], u1 = ap_[1], u2 = ap_[2], u3 = ap_[3]; \
    uint u4 = ap_[4], u5 = ap_[5], u6 = ap_[6], u7 = ap_[7]; \
    AH = mkbf8(__builtin_amdgcn_perm(u1,u0,0x05040100), __builtin_amdgcn_perm(u3,u2,0x05040100), \
               __builtin_amdgcn_perm(u5,u4,0x05040100), __builtin_amdgcn_perm(u7,u6,0x05040100)); \
    AL = mkbf8(__builtin_amdgcn_perm(u1,u0,0x07060302), __builtin_amdgcn_perm(u3,u2,0x07060302), \
               __builtin_amdgcn_perm(u5,u4,0x07060302), __builtin_amdgcn_perm(u7,u6,0x07060302)); }

// Load a 4-pair (h/l) B-fragment batch into a register array (8 bf16x8 = 32 VGPR).
#define LDB8(ARR, BHP, BLP) { \
    uint4 h0_=(BHP)[0], l0_=(BLP)[0], h1_=(BHP)[64], l1_=(BLP)[64]; \
    uint4 h2_=(BHP)[128], l2_=(BLP)[128], h3_=(BHP)[192], l3_=(BLP)[192]; \
    ARR[0]=mkbf8(h0_.x,h0_.y,h0_.z,h0_.w); ARR[1]=mkbf8(l0_.x,l0_.y,l0_.z,l0_.w); \
    ARR[2]=mkbf8(h1_.x,h1_.y,h1_.z,h1_.w); ARR[3]=mkbf8(l1_.x,l1_.y,l1_.z,l1_.w); \
    ARR[4]=mkbf8(h2_.x,h2_.y,h2_.z,h2_.w); ARR[5]=mkbf8(l2_.x,l2_.y,l2_.z,l2_.w); \
    ARR[6]=mkbf8(h3_.x,h3_.y,h3_.z,h3_.w); ARR[7]=mkbf8(l3_.x,l3_.y,l3_.z,l3_.w); }

// One A-tile vs all 4 preloaded B pairs: 12 MFMAs, 4 independent chains.
#define TILE4A(SRCP, mt, BA, D0, D1, D2, D3) { \
    bf16x8 Ah_, Al_; LDA(SRCP, mt, Ah_, Al_) \
    MF3(D0, Ah_, Al_, BA[0], BA[1]) MF3(D1, Ah_, Al_, BA[2], BA[3]) \
    MF3(D2, Ah_, Al_, BA[4], BA[5]) MF3(D3, Ah_, Al_, BA[6], BA[7]) }

// Full 64x64 += 64-rows x 32-K set with wave-uniform dead-tile skip.
#define DOSETA(SRCP, BA, ACC, SKA, SKB) { \
    TILE4A(SRCP, 0, BA, ACC[0], ACC[1], ACC[2], ACC[3]) \
    TILE4A(SRCP, 2, BA, ACC[8], ACC[9], ACC[10], ACC[11]) \
    if (!(SKA)) { TILE4A(SRCP, 1, BA, ACC[4], ACC[5], ACC[6], ACC[7]) } \
    if (!(SKB)) { TILE4A(SRCP, 3, BA, ACC[12], ACC[13], ACC[14], ACC[15]) } }

// ---------------- VFE (unchanged from round 6) ----------------
__global__ __launch_bounds__(64, 3) void vfe_kernel(
    const float* __restrict__ feat, const int* __restrict__ coors,
    const int* __restrict__ nvx,
    const float* __restrict__ W1,
    const ushort* __restrict__ w2fh, const ushort* __restrict__ w2fl,
    const ushort* __restrict__ w3fh, const ushort* __restrict__ w3fl,
    const ushort* __restrict__ w4fh, const ushort* __restrict__ w4fl,
    const float* __restrict__ fold,
    float* __restrict__ voxelwise, int* __restrict__ cnt,
    int* __restrict__ list, int* __restrict__ nact, int* __restrict__ act)
{
    __shared__ char ldsbuf[16896];   // x2s[2][64][33] u32
    int tid = threadIdx.x;
    int lane = tid;
    int quad = lane >> 4;
    int c0 = lane & 15;
    int v = blockIdx.x * 2 + (tid >> 5);
    int vA = blockIdx.x * 2;
    int t = tid & 31;
    uint*  x2s  = (uint*)ldsbuf;
    uint*  x2s1 = x2s + 2112;        // chunk1

    const float* fp = feat + (v*32 + t)*8;
    float4 fa = *(const float4*)(fp);
    float4 fb = *(const float4*)(fp+4);
    int numv = nvx[v];
    bf16x8 Bw2[4];
    {
        const uint4* bh2 = (const uint4*)w2fh + lane;
        const uint4* bl2 = (const uint4*)w2fl + lane;
        uint4 h0_=bh2[0], l0_=bl2[0], h1_=bh2[64], l1_=bl2[64];
        Bw2[0]=mkbf8(h0_.x,h0_.y,h0_.z,h0_.w); Bw2[1]=mkbf8(l0_.x,l0_.y,l0_.z,l0_.w);
        Bw2[2]=mkbf8(h1_.x,h1_.y,h1_.z,h1_.w); Bw2[3]=mkbf8(l1_.x,l1_.y,l1_.z,l1_.w);
    }

#define D1(o) float x1_##o; float m1_##o;
    REP8_0(D1)
#undef D1
#define FE1(o) { const float* w = W1 + (o)*8; \
    float ya = fa.x*w[0] + fa.y*w[1]; float yb = fa.z*w[2] + fa.w*w[3]; \
    float yc = fb.x*w[4] + fb.y*w[5]; float yd = fb.z*w[6] + fb.w*w[7]; \
    float yy = ((ya+yb)+(yc+yd)) * fold[(o)] + fold[8+(o)]; \
    x1_##o = mishf(yy); }
    REP8_0(FE1)
#undef FE1
#define P1(o) { float a = x1_##o; WMAX32(a); m1_##o = a; }
    REP8_0(P1)
#undef P1

    int nA = __builtin_amdgcn_readfirstlane(__shfl(numv, 0));
    int nB = __builtin_amdgcn_readfirstlane(__shfl(numv, 32));
    const bool skipA = (nA <= 16);
    const bool skipB = (nB <= 16);

#define S1(o) { x2s1[lane*33 + (o)] = splitbf(x1_##o); x2s1[lane*33 + 8 + (o)] = splitbf(m1_##o); }
    REP8_0(S1)
#undef S1

    bf16x8 BA[8], BB[8];
    {
        const uint4* bh3 = (const uint4*)w3fh + lane;
        const uint4* bl3 = (const uint4*)w3fl + lane;
        LDB8(BA, bh3, bl3)
    }

    f32x4 f2[8];
#pragma unroll
    for (int i = 0; i < 8; i++) f2[i] = (f32x4){0.f,0.f,0.f,0.f};
    {
        { bf16x8 Ah_,Al_; LDA2(x2s1,0,Ah_,Al_) MF3(f2[0],Ah_,Al_,Bw2[0],Bw2[1]) MF3(f2[1],Ah_,Al_,Bw2[2],Bw2[3]) }
        { bf16x8 Ah_,Al_; LDA2(x2s1,1,Ah_,Al_) MF3(f2[2],Ah_,Al_,Bw2[0],Bw2[1]) MF3(f2[3],Ah_,Al_,Bw2[2],Bw2[3]) }
        { bf16x8 Ah_,Al_; LDA2(x2s1,2,Ah_,Al_) MF3(f2[4],Ah_,Al_,Bw2[0],Bw2[1]) MF3(f2[5],Ah_,Al_,Bw2[2],Bw2[3]) }
        { bf16x8 Ah_,Al_; LDA2(x2s1,3,Ah_,Al_) MF3(f2[6],Ah_,Al_,Bw2[0],Bw2[1]) MF3(f2[7],Ah_,Al_,Bw2[2],Bw2[3]) }
    }

    {
        const uint4* bh3 = (const uint4*)w3fh + 256 + lane;
        const uint4* bl3 = (const uint4*)w3fl + 256 + lane;
        LDB8(BB, bh3, bl3)
    }

    float s2a = fold[16+c0], t2a = fold[48+c0];
    float s2b = fold[32+c0], t2b = fold[64+c0];
#define MSH4(s, SS, TT) { f2[s].x=mishf(f2[s].x*(SS)+(TT)); f2[s].y=mishf(f2[s].y*(SS)+(TT)); \
                          f2[s].z=mishf(f2[s].z*(SS)+(TT)); f2[s].w=mishf(f2[s].w*(SS)+(TT)); }
    MSH4(0,s2a,t2a) MSH4(1,s2b,t2b) MSH4(2,s2a,t2a) MSH4(3,s2b,t2b)
    MSH4(4,s2a,t2a) MSH4(5,s2b,t2b) MSH4(6,s2a,t2a) MSH4(7,s2b,t2b)
#undef MSH4

#define MX4(V) fmaxf(fmaxf((V).x,(V).y), fmaxf((V).z,(V).w))
    float aggA0 = fmaxf(MX4(f2[0]), MX4(f2[2]));
    float aggA1 = fmaxf(MX4(f2[1]), MX4(f2[3]));
    float aggB0 = fmaxf(MX4(f2[4]), MX4(f2[6]));
    float aggB1 = fmaxf(MX4(f2[5]), MX4(f2[7]));
#undef MX4
#define REDQ(p) p = fmaxf(p, __shfl_xor(p, 16)); p = fmaxf(p, __shfl_xor(p, 32));
    REDQ(aggA0) REDQ(aggA1) REDQ(aggB0) REDQ(aggB1)
#undef REDQ
    uint sgA0 = splitbf(aggA0), sgA1 = splitbf(aggA1);
    uint sgB0 = splitbf(aggB0), sgB1 = splitbf(aggB1);

#define ST2(mt, NVV, SG0, SG1) { \
    int rt_ = quad*4 + 16*((mt)&1); \
    int gr_ = (quad*4 + 16*(mt))*33; \
    float m0_=(rt_+0<(NVV))?1.f:0.f, m1_=(rt_+1<(NVV))?1.f:0.f; \
    float m2_=(rt_+2<(NVV))?1.f:0.f, m3_=(rt_+3<(NVV))?1.f:0.f; \
    f32x4 a_ = f2[(mt)*2], b_ = f2[(mt)*2+1]; \
    x2s[gr_    + c0] = splitbf(a_.x*m0_);  x2s[gr_    + c0+16] = splitbf(b_.x*m0_); \
    x2s[gr_+33 + c0] = splitbf(a_.y*m1_);  x2s[gr_+33 + c0+16] = splitbf(b_.y*m1_); \
    x2s[gr_+66 + c0] = splitbf(a_.z*m2_);  x2s[gr_+66 + c0+16] = splitbf(b_.z*m2_); \
    x2s[gr_+99 + c0] = splitbf(a_.w*m3_);  x2s[gr_+99 + c0+16] = splitbf(b_.w*m3_); \
    x2s1[gr_    + c0] = (m0_!=0.f)?(SG0):0u;  x2s1[gr_    + c0+16] = (m0_!=0.f)?(SG1):0u; \
    x2s1[gr_+33 + c0] = (m1_!=0.f)?(SG0):0u;  x2s1[gr_+33 + c0+16] = (m1_!=0.f)?(SG1):0u; \
    x2s1[gr_+66 + c0] = (m2_!=0.f)?(SG0):0u;  x2s1[gr_+66 + c0+16] = (m2_!=0.f)?(SG1):0u; \
    x2s1[gr_+99 + c0] = (m3_!=0.f)?(SG0):0u;  x2s1[gr_+99 + c0+16] = (m3_!=0.f)?(SG1):0u; }
    ST2(0, nA, sgA0, sgA1)
    ST2(2, nB, sgB0, sgB1)
    if (!skipA) { ST2(1, nA, sgA0, sgA1) }
    if (!skipB) { ST2(3, nB, sgB0, sgB1) }
#undef ST2

    f32x4 e[16];
#define EIN(i) e[i] = (f32x4){0.f,0.f,0.f,0.f};
    REP16_0(EIN)
#undef EIN
    DOSETA(x2s,  BA, e, skipA, skipB)
    DOSETA(x2s1, BB, e, skipA, skipB)

    {
        const uint4* bh4 = (const uint4*)w4fh + lane;
        const uint4* bl4 = (const uint4*)w4fl + lane;
        LDB8(BA, bh4, bl4)
    }

    uint* x3st = x2s1;
    f32x4 d[16];
#define DIN(i) d[i] = (f32x4){0.f,0.f,0.f,0.f};
    REP16_0(DIN)
#undef DIN

#define POST(TI, mt, nt) { \
    float s_ = fold[80 + c0 + 16*(nt)], tb_ = fold[144 + c0 + 16*(nt)]; \
    int col_ = c0 + 16*((nt)&1); \
    int rowb_ = quad*4 + 16*(mt); \
    x3st[(rowb_+0)*33 + col_] = splitbf(mishf(e[TI].x * s_ + tb_)); \
    x3st[(rowb_+1)*33 + col_] = splitbf(mishf(e[TI].y * s_ + tb_)); \
    x3st[(rowb_+2)*33 + col_] = splitbf(mishf(e[TI].z * s_ + tb_)); \
    x3st[(rowb_+3)*33 + col_] = splitbf(mishf(e[TI].w * s_ + tb_)); }

    {
        POST(0,0,0)  POST(1,0,1)
        POST(8,2,0)  POST(9,2,1)
        if (!skipA) { POST(4,1,0)  POST(5,1,1) }
        if (!skipB) { POST(12,3,0) POST(13,3,1) }
        DOSETA(x3st, BA, d, skipA, skipB)
    }
    {
        const uint4* bh4 = (const uint4*)w4fh + 256 + lane;
        const uint4* bl4 = (const uint4*)w4fl + 256 + lane;
        LDB8(BB, bh4, bl4)
    }
    {
        POST(2,0,2)  POST(3,0,3)
        POST(10,2,2) POST(11,2,3)
        if (!skipA) { POST(6,1,2)  POST(7,1,3) }
        if (!skipB) { POST(14,3,2) POST(15,3,3) }
        DOSETA(x3st, BB, d, skipA, skipB)
    }
#undef POST

    float s0f = fold[208+c0],    t0f = fold[272+c0];
    float s1f = fold[208+16+c0], t1f = fold[272+16+c0];
    float s2f = fold[208+32+c0], t2f = fold[272+32+c0];
    float s3f = fold[208+48+c0], t3f = fold[272+48+c0];
    float piA = skipA ? 0.f : -3.4e38f;
    float piB = skipB ? 0.f : -3.4e38f;
    float pA0=piA, pA1=piA, pA2=piA, pA3=piA;
    float pB0=piB, pB1=piB, pB2=piB, pB3=piB;

#define RECON(u) (__uint_as_float((u)<<16) + __uint_as_float((u) & 0xFFFF0000u))
#define FTP(D, mt, nt, SS, TT, PV) { \
    int nv = ((mt) >> 1) ? nB : nA; \
    int rf = quad*4 + 16*(mt); \
    int rt = quad*4 + 16*((mt)&1); \
    int cb = c0 + 16*(nt); \
    float m0=(rt+0<nv)?1.f:0.f, m1=(rt+1<nv)?1.f:0.f, m2=(rt+2<nv)?1.f:0.f, m3=(rt+3<nv)?1.f:0.f; \
    uint ua_ = x2s[(rf+0)*33 + cb], ub_ = x2s[(rf+1)*33 + cb]; \
    uint uc_ = x2s[(rf+2)*33 + cb], ud_ = x2s[(rf+3)*33 + cb]; \
    float y0 = mishf(D.x*SS + TT)*m0 + RECON(ua_); \
    float y1 = mishf(D.y*SS + TT)*m1 + RECON(ub_); \
    float y2 = mishf(D.z*SS + TT)*m2 + RECON(uc_); \
    float y3 = mishf(D.w*SS + TT)*m3 + RECON(ud_); \
    PV = fmaxf(PV, fmaxf(fmaxf(y0,y1), fmaxf(y2,y3))); }

#define FTA(D, mt, nt, SS, TT, AG, PV) { \
    int nv = ((mt) >> 1) ? nB : nA; \
    int rt = quad*4 + 16*((mt)&1); \
    float m0=(rt+0<nv)?1.f:0.f, m1=(rt+1<nv)?1.f:0.f, m2=(rt+2<nv)?1.f:0.f, m3=(rt+3<nv)?1.f:0.f; \
    float y0 = (mishf(D.x*SS + TT) + AG)*m0; \
    float y1 = (mishf(D.y*SS + TT) + AG)*m1; \
    float y2 = (mishf(D.z*SS + TT) + AG)*m2; \
    float y3 = (mishf(D.w*SS + TT) + AG)*m3; \
    PV = fmaxf(PV, fmaxf(fmaxf(y0,y1), fmaxf(y2,y3))); }

    FTP(d[0], 0, 0, s0f, t0f, pA0)  FTP(d[1], 0, 1, s1f, t1f, pA1)
    FTA(d[2], 0, 2, s2f, t2f, aggA0, pA2)  FTA(d[3], 0, 3, s3f, t3f, aggA1, pA3)
    if (!skipA) {
        FTP(d[4], 1, 0, s0f, t0f, pA0)  FTP(d[5], 1, 1, s1f, t1f, pA1)
        FTA(d[6], 1, 2, s2f, t2f, aggA0, pA2)  FTA(d[7], 1, 3, s3f, t3f, aggA1, pA3)
    }
    FTP(d[8], 2, 0, s0f, t0f, pB0)  FTP(d[9], 2, 1, s1f, t1f, pB1)
    FTA(d[10], 2, 2, s2f, t2f, aggB0, pB2)  FTA(d[11], 2, 3, s3f, t3f, aggB1, pB3)
    if (!skipB) {
        FTP(d[12], 3, 0, s0f, t0f, pB0)  FTP(d[13], 3, 1, s1f, t1f, pB1)
        FTA(d[14], 3, 2, s2f, t2f, aggB0, pB2)  FTA(d[15], 3, 3, s3f, t3f, aggB1, pB3)
    }
#undef FTP
#undef FTA
#undef RECON

#define RED(p) p = fmaxf(p, __shfl_xor(p, 16)); p = fmaxf(p, __shfl_xor(p, 32));
    RED(pA0) RED(pA1) RED(pA2) RED(pA3) RED(pB0) RED(pB1) RED(pB2) RED(pB3)
#undef RED

    if (quad == 0) {
        float* vwA = voxelwise + vA*64;
        vwA[c0] = pA0; vwA[c0+16] = pA1; vwA[c0+32] = pA2; vwA[c0+48] = pA3;
        float* vwB = voxelwise + (vA+1)*64;
        vwB[c0] = pB0; vwB[c0+16] = pB1; vwB[c0+32] = pB2; vwB[c0+48] = pB3;
    }

    if (t == 0) {
        int cell = coors[v*2] * BEVW + coors[v*2+1];
        int pos = atomicAdd(&cnt[cell], 1);
        if (pos < 16) list[cell*16 + pos] = v;
        if (pos == 0) { int k = atomicAdd(nact, 1); act[k] = cell; }
    }
}

// ---------------- bfe_back: fused bfe_front + bfe3 (MFMA), x19 into x17g ----------------
// Block = 512 thr (8 waves) = 64 cells. Phase 1: bfe_front math verbatim, 8
// cells/wave, x17 written split-bf16 straight into LDS (eliminates the 18.5MB
// x17 global write+read and the 10000-block bfe_front launch). Phase 2/3: the
// two 64x128x128 fe passes on MFMA (vfe's validated LDA/MF3/C-layout; B-frags
// built in-registers from bfe3_W with the same perm-pack as LDA, reused for
// both passes since the reference applies bfe3 twice).
__global__ __launch_bounds__(512) void bfe_back(
    const int* __restrict__ nactp, const int* __restrict__ act,
    const int* __restrict__ cnt, const int* __restrict__ list,
    const float* __restrict__ voxelwise,
    const float* __restrict__ W1g, const float* __restrict__ W2g,
    const float* __restrict__ W3, const float* __restrict__ fold,
    float* __restrict__ x17g, int* __restrict__ idx)
{
    __shared__ uint XA[4*2112];   // 4 K-chunks of [64 rows][33] split-u32 (33792 B)
    int tid = threadIdx.x;
    int n_act = *nactp;
    int cb = blockIdx.x * 64;
    int wv = tid >> 6;
    int lane = tid & 63;
    int quad = lane >> 4, c0 = lane & 15;
    int g = lane >> 2, ii = lane & 3;

    // ---- phase 1: bfe_front for 8 cells per wave; x17 split-bf16 -> LDS ----
    for (int r = 0; r < 8; r++) {
        int ci = (wv << 3) + r;
        int aidx = cb + ci;
        uint z0u = 0u, z1u = 0u;
        if (aidx < n_act) {
            int cell = act[aidx];
            int numv = min(cnt[cell], 16);
            if (lane == 0) idx[cell] = aidx + 1;
            int myidx = (lane < numv) ? list[cell*16 + lane] : (0x40000000 + lane);
            int rank = 0;
            for (int j = 0; j < numv; j++) { int vj = __shfl(myidx, j); rank += (vj < myidx) ? 1 : 0; }
            if (lane >= numv) rank = lane;
            int sorted = __builtin_amdgcn_ds_permute(rank << 2, myidx);

#define YD(q) float y_##q = 0.f;
            REP16_0(YD)
#undef YD
            for (int p = 0; p < numv; p++) {
                int sv = __shfl(sorted, p);
                float val = voxelwise[sv*64 + lane];
                const float* w = W1g + g*256 + p;
#define BF1(q) y_##q += val * w[(q)*16];
                REP16_0(BF1)
#undef BF1
            }
#define BN1(q) { float yy = y_##q * fold[592 + g*16 + (q)] + fold[848 + g*16 + (q)]; \
    yy = mishf(yy); y_##q = ((q) < numv) ? yy : 0.f; }
            REP16_0(BN1)
#undef BN1
            float z0 = 0.f, z1 = 0.f;
#define BF2(p) z0 += y_##p * W2g[g*32 + (p)]; z1 += y_##p * W2g[g*32 + 16 + (p)];
            REP16_0(BF2)
#undef BF2
            z0 = mishf(z0 * fold[1104 + g*2 + 0] + fold[1136 + g*2 + 0]);
            z1 = mishf(z1 * fold[1104 + g*2 + 1] + fold[1136 + g*2 + 1]);
            z0u = splitbf(z0); z1u = splitbf(z1);
        }
        // x17 col k0 = ii*32 + g*2 -> chunk ii, col g*2 (and +1)
        XA[ii*2112 + ci*33 + g*2]     = z0u;
        XA[ii*2112 + ci*33 + g*2 + 1] = z1u;
    }
    __syncthreads();

    // ---- B fragments for bfe3_W: wave wv owns channels nch = c0 + 16*wv ----
    int nch = c0 + (wv << 4);
    float s5 = fold[336 + nch], t5 = fold[464 + nch];
#define BLD(KC) bf16x8 B3h##KC, B3l##KC; { \
    const float* wr = W3 + nch*128 + (KC)*32 + quad*8; \
    float4 wa = *(const float4*)wr; float4 wb = *(const float4*)(wr+4); \
    uint u0=splitbf(wa.x), u1=splitbf(wa.y), u2=splitbf(wa.z), u3=splitbf(wa.w); \
    uint u4=splitbf(wb.x), u5=splitbf(wb.y), u6=splitbf(wb.z), u7=splitbf(wb.w); \
    B3h##KC = mkbf8(__builtin_amdgcn_perm(u1,u0,0x05040100), __builtin_amdgcn_perm(u3,u2,0x05040100), \
                    __builtin_amdgcn_perm(u5,u4,0x05040100), __builtin_amdgcn_perm(u7,u6,0x05040100)); \
    B3l##KC = mkbf8(__builtin_amdgcn_perm(u1,u0,0x07060302), __builtin_amdgcn_perm(u3,u2,0x07060302), \
                    __builtin_amdgcn_perm(u5,u4,0x07060302), __builtin_amdgcn_perm(u7,u6,0x07060302)); }
    BLD(0) BLD(1) BLD(2) BLD(3)
#undef BLD

#define KSTEP(KC, Q0, Q1, Q2, Q3) { \
    const uint* ch_ = XA + (KC)*2112; \
    bf16x8 Ah0,Al0,Ah1,Al1,Ah2,Al2,Ah3,Al3; \
    LDA(ch_,0,Ah0,Al0) LDA(ch_,1,Ah1,Al1) LDA(ch_,2,Ah2,Al2) LDA(ch_,3,Ah3,Al3) \
    MF3(Q0,Ah0,Al0,B3h##KC,B3l##KC) MF3(Q1,Ah1,Al1,B3h##KC,B3l##KC) \
    MF3(Q2,Ah2,Al2,B3h##KC,B3l##KC) MF3(Q3,Ah3,Al3,B3h##KC,B3l##KC) }

#define PASS3(Q0,Q1,Q2,Q3) \
    Q0 = (f32x4){0.f,0.f,0.f,0.f}; Q1 = Q0; Q2 = Q0; Q3 = Q0; \
    KSTEP(0,Q0,Q1,Q2,Q3) KSTEP(1,Q0,Q1,Q2,Q3) KSTEP(2,Q0,Q1,Q2,Q3) KSTEP(3,Q0,Q1,Q2,Q3)

#define ACT4(Q) { Q.x = mishf(Q.x*s5+t5); Q.y = mishf(Q.y*s5+t5); \
                  Q.z = mishf(Q.z*s5+t5); Q.w = mishf(Q.w*s5+t5); }

    // ---- pass 1 (x18 = fe(x17)) ----
    f32x4 q0, q1, q2, q3;
    PASS3(q0,q1,q2,q3)
    ACT4(q0) ACT4(q1) ACT4(q2) ACT4(q3)
    __syncthreads();   // all waves done reading XA before overwrite
    {
        // C layout: row = quad*4 + reg + 16*mt, col(ch) = nch -> chunk wv>>1, cc (wv&1)*16+c0
        uint* dst = XA + (wv >> 1)*2112 + ((wv & 1) << 4) + c0;
        int rb = quad*4;
        dst[(rb+0)*33]      = splitbf(q0.x); dst[(rb+1)*33]      = splitbf(q0.y);
        dst[(rb+2)*33]      = splitbf(q0.z); dst[(rb+3)*33]      = splitbf(q0.w);
        dst[(rb+16)*33]     = splitbf(q1.x); dst[(rb+17)*33]     = splitbf(q1.y);
        dst[(rb+18)*33]     = splitbf(q1.z); dst[(rb+19)*33]     = splitbf(q1.w);
        dst[(rb+32)*33]     = splitbf(q2.x); dst[(rb+33)*33]     = splitbf(q2.y);
        dst[(rb+34)*33]     = splitbf(q2.z); dst[(rb+35)*33]     = splitbf(q2.w);
        dst[(rb+48)*33]     = splitbf(q3.x); dst[(rb+49)*33]     = splitbf(q3.y);
        dst[(rb+50)*33]     = splitbf(q3.z); dst[(rb+51)*33]     = splitbf(q3.w);
    }
    __syncthreads();

    // ---- pass 2 (x19 = fe(x18)), same W/bn ----
    PASS3(q0,q1,q2,q3)
    ACT4(q0) ACT4(q1) ACT4(q2) ACT4(q3)
#undef ACT4
#undef PASS3
#undef KSTEP

    // store x19 fp32 to x17g[cell][128]
    {
        size_t rb = (size_t)(cb + quad*4);
        x17g[(rb+0)*128 + nch] = q0.x;  x17g[(rb+1)*128 + nch] = q0.y;
        x17g[(rb+2)*128 + nch] = q0.z;  x17g[(rb+3)*128 + nch] = q0.w;
        x17g[(rb+16)*128 + nch] = q1.x; x17g[(rb+17)*128 + nch] = q1.y;
        x17g[(rb+18)*128 + nch] = q1.z; x17g[(rb+19)*128 + nch] = q1.w;
        x17g[(rb+32)*128 + nch] = q2.x; x17g[(rb+33)*128 + nch] = q2.y;
        x17g[(rb+34)*128 + nch] = q2.z; x17g[(rb+35)*128 + nch] = q2.w;
        x17g[(rb+48)*128 + nch] = q3.x; x17g[(rb+49)*128 + nch] = q3.y;
        x17g[(rb+50)*128 + nch] = q3.z; x17g[(rb+51)*128 + nch] = q3.w;
    }
}

// ---------------- bev_write: tiled transpose-scatter (replaces out memset) ----------------
__global__ __launch_bounds__(512, 2) void bev_write(
    const int* __restrict__ idx, const float* __restrict__ x19c,
    float* __restrict__ out)
{
    __shared__ float XT[128*65];
    int bid = blockIdx.x;
    int cx = bid % BEVW;
    int cy0 = (bid / BEVW) << 6;
    int tid = threadIdx.x;

    int cell_l = tid >> 3;
    int chq = (tid & 7) << 4;
    int cy = cy0 + cell_l;
    float4 v0 = make_float4(0.f,0.f,0.f,0.f), v1 = v0, v2 = v0, v3 = v0;
    if (cy < BEVH) {
        int ai = idx[cy*BEVW + cx] - 1;
        if (ai >= 0) {
            const float4* src = (const float4*)(x19c + (size_t)ai*128 + chq);
            v0 = src[0]; v1 = src[1]; v2 = src[2]; v3 = src[3];
        }
    }
    float* d = XT + chq*65 + cell_l;
    d[0*65]=v0.x;  d[1*65]=v0.y;  d[2*65]=v0.z;  d[3*65]=v0.w;
    d[4*65]=v1.x;  d[5*65]=v1.y;  d[6*65]=v1.z;  d[7*65]=v1.w;
    d[8*65]=v2.x;  d[9*65]=v2.y;  d[10*65]=v2.z; d[11*65]=v2.w;
    d[12*65]=v3.x; d[13*65]=v3.y; d[14*65]=v3.z; d[15*65]=v3.w;
    __syncthreads();

    int wv2 = tid >> 6, lane = tid & 63;
    int cyw = cy0 + lane;
    if (cyw < BEVH) {
        float* op = out + cx*BEVH + cyw;
#pragma unroll
        for (int k = 0; k < 16; k++) {
            int c = (wv2 << 4) + k;
            op[(size_t)c*NCELL] = XT[c*65 + lane];
        }
    }
}

extern "C" void kernel_launch(void* const* d_in, const int* in_sizes, int n_in,
                              void* d_out, int out_size, void* d_ws, size_t ws_size,
                              hipStream_t stream) {
    const float* features = (const float*)d_in[0];
    const int*   coors    = (const int*)d_in[1];
    const int*   num_vox  = (const int*)d_in[2];
    const float* vfe1_W   = (const float*)d_in[3];
    const float* vfe1_bn  = (const float*)d_in[4];
    const float* vfe2_W   = (const float*)d_in[5];
    const float* vfe2_bn  = (const float*)d_in[6];
    const float* vfe3_W   = (const float*)d_in[7];
    const float* vfe3_bn  = (const float*)d_in[8];
    const float* vfe4_W   = (const float*)d_in[9];
    const float* vfe4_bn  = (const float*)d_in[10];
    const float* bfe1_W   = (const float*)d_in[11];
    const float* bfe1_bn  = (const float*)d_in[12];
    const float* bfe2_W   = (const float*)d_in[13];
    const float* bfe2_bn  = (const float*)d_in[14];
    const float* bfe3_W   = (const float*)d_in[15];
    const float* bfe3_bn  = (const float*)d_in[16];
    float* out = (float*)d_out;

    char* ws = (char*)d_ws;
    int*    nact      = (int*)ws;                       // zeroed
    int*    cnt       = (int*)(ws + 256);               // zeroed
    int*    idx       = (int*)(ws + 857344);            // zeroed (aidx+1 encoding)
    int*    list      = (int*)(ws + 1714432);
    float*  voxelwise = (float*)(ws + 15427840);
    int*    act       = (int*)(ws + 25667840);
    float*  x17g      = (float*)(ws + 25827840);
    float*  fold      = (float*)(ws + 46307840);
    ushort* w4fh      = (ushort*)(ws + 46312512);
    ushort* w4fl      = (ushort*)(ws + 46320704);
    ushort* w3fh      = (ushort*)(ws + 46328896);
    ushort* w3fl      = (ushort*)(ws + 46337088);
    ushort* w2fh      = (ushort*)(ws + 46345280);
    ushort* w2fl      = (ushort*)(ws + 46347328);

    (void)hipMemsetAsync(ws, 0, 1714432, stream);   // nact + cnt + idx in one shot

    setup_kernel<<<1, 256, 0, stream>>>(vfe1_bn, vfe2_bn, vfe3_bn, vfe4_bn,
                                        bfe1_bn, bfe2_bn, bfe3_bn, vfe4_W, vfe3_W, vfe2_W,
                                        fold, w4fh, w4fl, w3fh, w3fl, w2fh, w2fl);
    vfe_kernel<<<NVOX/2, 64, 0, stream>>>(features, coors, num_vox,
                                          vfe1_W, w2fh, w2fl, w3fh, w3fl, w4fh, w4fl, fold,
                                          voxelwise, cnt, list, nact, act);
    bfe_back<<<(NVOX+63)/64, 512, 0, stream>>>(nact, act, cnt, list, voxelwise,
                                               bfe1_W, bfe2_W, bfe3_W, fold, x17g, idx);
    bev_write<<<BEVW*8, 512, 0, stream>>>(idx, x17g, out);
}

// Round 8
// 504.801 us; speedup vs baseline: 1.0123x; 1.0123x over previous
//
#include <hip/hip_runtime.h>

#define BEVW 432
#define BEVH 496
#define NCELL (BEVW*BEVH)      // 214272
#define NVOX  40000
#define EPSB  1e-5f

typedef float f32x2 __attribute__((ext_vector_type(2)));
typedef float f32x4 __attribute__((ext_vector_type(4)));
typedef unsigned int u32x4 __attribute__((ext_vector_type(4)));
typedef short bf16x8 __attribute__((ext_vector_type(8)));

// ---- repeat macros ----
#define REP8_0(M)  M(0) M(1) M(2) M(3) M(4) M(5) M(6) M(7)
#define REP8_8(M)  M(8) M(9) M(10) M(11) M(12) M(13) M(14) M(15)
#define REP16_0(M)  REP8_0(M)  REP8_8(M)

// ---------------- workspace layout (bytes) ----------------
// 0        : int nact (zeroed by setup)
// 256      : int cnt[NCELL]  (zeroed by setup)    -> 857344
// 857344   : int idx[NCELL]  (zeroed; aidx+1)     -> 1714432
// 1714432  : int list[NCELL*16]                   -> 15427840
// 15427840 : float voxelwise[NVOX*64]             -> 25667840
// 25667840 : int act[NVOX]                        -> 25827840
// 25827840 : float x17g[NVOX*128] (x19 lives here) -> 46307840
// 46307840 : float fold[1168]
// 46312512 : w4fh | 46320704: w4fl | 46328896: w3fh | 46337088: w3fl
// 46345280 : w2fh[1024] | 46347328 : w2fl[1024]

__device__ __forceinline__ float mishf(float y) {
    float e = __expf(fminf(y, 40.f));
    float n = e * (e + 2.f);
    return y * n * __builtin_amdgcn_rcpf(n + 2.f);
}

template <int CTRL>
__device__ __forceinline__ float dppmaxf(float a) {
    int p = __builtin_amdgcn_update_dpp(0, __float_as_int(a), CTRL, 0xF, 0xF, true);
    return fmaxf(a, __int_as_float(p));
}
#define WMAX32(a) { \
    a = dppmaxf<0xB1>(a); \
    a = dppmaxf<0x4E>(a); \
    a = dppmaxf<0x141>(a); \
    a = dppmaxf<0x140>(a); \
    a = fmaxf(a, __int_as_float(__builtin_amdgcn_ds_swizzle(__float_as_int(a), 0x401F))); }

__device__ __forceinline__ bf16x8 mkbf8(uint a, uint b, uint c, uint d) {
    u32x4 t = {a, b, c, d};
    return __builtin_bit_cast(bf16x8, t);
}

// split fp32 -> (hi bf16 | lo bf16 << 16). Hi = TRUNCATION (1 op); lo = x - hi is
// then exact in fp32, RNE'd to bf16. Combined representation err ~2^-17 rel.
__device__ __forceinline__ uint splitbf(float x) {
    uint rh = __float_as_uint(x) & 0xFFFF0000u;
    float lof = x - __uint_as_float(rh);
    uint ul = __float_as_uint(lof);
    uint rl = (ul + 0x7FFFu + ((ul >> 16) & 1u)) >> 16;
    return (rh >> 16) | (rl << 16);
}

// fold layout: vfe1 s@0 t@8 | vfe2 s@16 t@48 | vfe3 s@80 t@144 | vfe4 s@208 t@272
// bfe3 s@336 t@464 | bfe1 s@592 t@848 | bfe2 s@1104 t@1136
// R8: widened to 48 blocks (was 1 block gating the grid) + absorbs the
// nact/cnt/idx zero-fill (removes the separate hipMemsetAsync dispatch).
__global__ __launch_bounds__(256) void setup_kernel(
    const float* __restrict__ vbn1, const float* __restrict__ vbn2,
    const float* __restrict__ vbn3, const float* __restrict__ vbn4,
    const float* __restrict__ bbn1, const float* __restrict__ bbn2,
    const float* __restrict__ bbn3, const float* __restrict__ W4,
    const float* __restrict__ W3g, const float* __restrict__ W2g,
    float* __restrict__ fold, ushort* __restrict__ w4fh, ushort* __restrict__ w4fl,
    ushort* __restrict__ w3fh, ushort* __restrict__ w3fl,
    ushort* __restrict__ w2fh, ushort* __restrict__ w2fl,
    uint4* __restrict__ zbase)
{
    int tid = threadIdx.x;
    int gid = blockIdx.x * 256 + tid;
    int gsz = gridDim.x * 256;

    // zero nact + cnt + idx (1714432 B = 107152 uint4), replaces hipMemsetAsync
    for (int i = gid; i < 107152; i += gsz)
        zbase[i] = (uint4){0u, 0u, 0u, 0u};

    if (blockIdx.x == 0) {
        if (tid < 8)  { float s = vbn1[tid]/sqrtf(vbn1[24+tid]+EPSB);  fold[tid]      = s; fold[8+tid]   = vbn1[8+tid]  - vbn1[16+tid]*s; }
        if (tid < 32) { float s = vbn2[tid]/sqrtf(vbn2[96+tid]+EPSB);  fold[16+tid]   = s; fold[48+tid]  = vbn2[32+tid] - vbn2[64+tid]*s; }
        if (tid < 64) { float s = vbn3[tid]/sqrtf(vbn3[192+tid]+EPSB); fold[80+tid]   = s; fold[144+tid] = vbn3[64+tid] - vbn3[128+tid]*s; }
        if (tid < 64) { float s = vbn4[tid]/sqrtf(vbn4[192+tid]+EPSB); fold[208+tid]  = s; fold[272+tid] = vbn4[64+tid] - vbn4[128+tid]*s; }
        if (tid < 128){ float s = bbn3[tid]/sqrtf(bbn3[384+tid]+EPSB); fold[336+tid]  = s; fold[464+tid] = bbn3[128+tid]- bbn3[256+tid]*s; }
        { int g = tid >> 4, q = tid & 15;
          const float* b = bbn1 + g*64;
          float s = b[q]/sqrtf(b[48+q]+EPSB);
          fold[592+tid] = s; fold[848+tid] = b[16+q] - b[32+q]*s; }
        if (tid < 32) { int g = tid >> 1, c = tid & 1;
          const float* b = bbn2 + g*8;
          float s = b[c]/sqrtf(b[6+c]+EPSB);
          fold[1104+tid] = s; fold[1136+tid] = b[2+c] - b[4+c]*s; }
    }

    // B-fragments (B[k][n] = W[n][k]) split bf16 hi/lo, for W4^T and W3^T (vfe).
    // frag idx = ((kc*4 + nt)*64 + lane)*8 + j ; n = (lane&15)+16nt ; k = kc*32 + (lane>>4)*8 + j
    for (int i = gid; i < 4096; i += gsz) {
        int j = i & 7, ln = (i >> 3) & 63, nt = (i >> 9) & 3, kc = i >> 11;
        int n = (ln & 15) + nt*16;
        int k = kc*32 + (ln >> 4)*8 + j;
        {
            float val = W4[n*64 + k];
            uint u = splitbf(val);
            w4fh[i] = (ushort)(u & 0xFFFFu);
            w4fl[i] = (ushort)(u >> 16);
        }
        {
            float val = W3g[n*64 + k];
            uint u = splitbf(val);
            w3fh[i] = (ushort)(u & 0xFFFFu);
            w3fl[i] = (ushort)(u >> 16);
        }
    }

    // W2 B-fragments: K=16 padded to 32 with ZERO weights (k>=16 -> 0), N=32.
    for (int i = gid; i < 1024; i += gsz) {
        int j = i & 7, ln = (i >> 3) & 63, nt = (i >> 9) & 1;
        int n = (ln & 15) + nt*16;
        int k = (ln >> 4)*8 + j;
        float val = (k < 16) ? W2g[n*16 + k] : 0.f;
        uint u = splitbf(val);
        w2fh[i] = (ushort)(u & 0xFFFFu);
        w2fl[i] = (ushort)(u >> 16);
    }
}

#define MF3(D, AH, AL, BH, BL) \
    D = __builtin_amdgcn_mfma_f32_16x16x32_bf16(AL, BH, D, 0, 0, 0); \
    D = __builtin_amdgcn_mfma_f32_16x16x32_bf16(AH, BL, D, 0, 0, 0); \
    D = __builtin_amdgcn_mfma_f32_16x16x32_bf16(AH, BH, D, 0, 0, 0);

// Load one A-tile (16 rows) from LDS rows (stride 33) and pack hi/lo bf16 frags.
#define LDA(SRCP, mt, AH, AL) { \
    const uint* ap_ = (SRCP) + ((lane & 15) + 16*(mt))*33 + quad*8; \
    uint u0 = ap_[0], u1 = ap_[1], u2 = ap_[2], u3 = ap_[3]; \
    uint u4 = ap_[4], u5 = ap_[5], u6 = ap_[6], u7 = ap_[7]; \
    AH = mkbf8(__builtin_amdgcn_perm(u1,u0,0x05040100), __builtin_amdgcn_perm(u3,u2,0x05040100), \
               __builtin_amdgcn_perm(u5,u4,0x05040100), __builtin_amdgcn_perm(u7,u6,0x05040100)); \
    AL = mkbf8(__builtin_amdgcn_perm(u1,u0,0x07060302), __builtin_amdgcn_perm(u3,u2,0x07060302), \
               __builtin_amdgcn_perm(u5,u4,0x07060302), __builtin_amdgcn_perm(u7,u6,0x07060302)); }

// fe2 A-tile: K=16 real data in cols 0-15. Quads 2,3 (k 16-31) RE-READ cols 0-15
// ((quad&1) addressing) so A stays finite; their B weights are exactly 0.
#define LDA2(SRCP, mt, AH, AL) { \
    const uint* ap_ = (SRCP) + ((lane & 15) + 16*(mt))*33 + (quad & 1)*8; \
    uint u0 = ap_[0], u1 = ap_[1], u2 = ap_[2], u3 = ap_[3]; \
    uint u4 = ap_[4], u5 = ap_[5], u6 = ap_[6], u7 = ap_[7]; \
    AH = mkbf8(__builtin_amdgcn_perm(u1,u0,0x05040100), __builtin_amdgcn_perm(u3,u2,0x05040100), \
               __builtin_amdgcn_perm(u5,u4,0x05040100), __builtin_amdgcn_perm(u7,u6,0x05040100)); \
    AL = mkbf8(__builtin_amdgcn_perm(u1,u0,0x07060302), __builtin_amdgcn_perm(u3,u2,0x07060302), \
               __builtin_amdgcn_perm(u5,u4,0x07060302), __builtin_amdgcn_perm(u7,u6,0x07060302)); }

// Load a 4-pair (h/l) B-fragment batch into a register array (8 bf16x8 = 32 VGPR).
#define LDB8(ARR, BHP, BLP) { \
    uint4 h0_=(BHP)[0], l0_=(BLP)[0], h1_=(BHP)[64], l1_=(BLP)[64]; \
    uint4 h2_=(BHP)[128], l2_=(BLP)[128], h3_=(BHP)[192], l3_=(BLP)[192]; \
    ARR[0]=mkbf8(h0_.x,h0_.y,h0_.z,h0_.w); ARR[1]=mkbf8(l0_.x,l0_.y,l0_.z,l0_.w); \
    ARR[2]=mkbf8(h1_.x,h1_.y,h1_.z,h1_.w); ARR[3]=mkbf8(l1_.x,l1_.y,l1_.z,l1_.w); \
    ARR[4]=mkbf8(h2_.x,h2_.y,h2_.z,h2_.w); ARR[5]=mkbf8(l2_.x,l2_.y,l2_.z,l2_.w); \
    ARR[6]=mkbf8(h3_.x,h3_.y,h3_.z,h3_.w); ARR[7]=mkbf8(l3_.x,l3_.y,l3_.z,l3_.w); }

// One A-tile vs all 4 preloaded B pairs: 12 MFMAs, 4 independent chains.
#define TILE4A(SRCP, mt, BA, D0, D1, D2, D3) { \
    bf16x8 Ah_, Al_; LDA(SRCP, mt, Ah_, Al_) \
    MF3(D0, Ah_, Al_, BA[0], BA[1]) MF3(D1, Ah_, Al_, BA[2], BA[3]) \
    MF3(D2, Ah_, Al_, BA[4], BA[5]) MF3(D3, Ah_, Al_, BA[6], BA[7]) }

// Full 64x64 += 64-rows x 32-K set with wave-uniform dead-tile skip.
#define DOSETA(SRCP, BA, ACC, SKA, SKB) { \
    TILE4A(SRCP, 0, BA, ACC[0], ACC[1], ACC[2], ACC[3]) \
    TILE4A(SRCP, 2, BA, ACC[8], ACC[9], ACC[10], ACC[11]) \
    if (!(SKA)) { TILE4A(SRCP, 1, BA, ACC[4], ACC[5], ACC[6], ACC[7]) } \
    if (!(SKB)) { TILE4A(SRCP, 3, BA, ACC[12], ACC[13], ACC[14], ACC[15]) } }

// ---------------- VFE (unchanged from rounds 6/7) ----------------
__global__ __launch_bounds__(64, 3) void vfe_kernel(
    const float* __restrict__ feat, const int* __restrict__ coors,
    const int* __restrict__ nvx,
    const float* __restrict__ W1,
    const ushort* __restrict__ w2fh, const ushort* __restrict__ w2fl,
    const ushort* __restrict__ w3fh, const ushort* __restrict__ w3fl,
    const ushort* __restrict__ w4fh, const ushort* __restrict__ w4fl,
    const float* __restrict__ fold,
    float* __restrict__ voxelwise, int* __restrict__ cnt,
    int* __restrict__ list, int* __restrict__ nact, int* __restrict__ act)
{
    __shared__ char ldsbuf[16896];   // x2s[2][64][33] u32
    int tid = threadIdx.x;
    int lane = tid;
    int quad = lane >> 4;
    int c0 = lane & 15;
    int v = blockIdx.x * 2 + (tid >> 5);
    int vA = blockIdx.x * 2;
    int t = tid & 31;
    uint*  x2s  = (uint*)ldsbuf;
    uint*  x2s1 = x2s + 2112;        // chunk1

    const float* fp = feat + (v*32 + t)*8;
    float4 fa = *(const float4*)(fp);
    float4 fb = *(const float4*)(fp+4);
    int numv = nvx[v];
    bf16x8 Bw2[4];
    {
        const uint4* bh2 = (const uint4*)w2fh + lane;
        const uint4* bl2 = (const uint4*)w2fl + lane;
        uint4 h0_=bh2[0], l0_=bl2[0], h1_=bh2[64], l1_=bl2[64];
        Bw2[0]=mkbf8(h0_.x,h0_.y,h0_.z,h0_.w); Bw2[1]=mkbf8(l0_.x,l0_.y,l0_.z,l0_.w);
        Bw2[2]=mkbf8(h1_.x,h1_.y,h1_.z,h1_.w); Bw2[3]=mkbf8(l1_.x,l1_.y,l1_.z,l1_.w);
    }

#define D1(o) float x1_##o; float m1_##o;
    REP8_0(D1)
#undef D1
#define FE1(o) { const float* w = W1 + (o)*8; \
    float ya = fa.x*w[0] + fa.y*w[1]; float yb = fa.z*w[2] + fa.w*w[3]; \
    float yc = fb.x*w[4] + fb.y*w[5]; float yd = fb.z*w[6] + fb.w*w[7]; \
    float yy = ((ya+yb)+(yc+yd)) * fold[(o)] + fold[8+(o)]; \
    x1_##o = mishf(yy); }
    REP8_0(FE1)
#undef FE1
#define P1(o) { float a = x1_##o; WMAX32(a); m1_##o = a; }
    REP8_0(P1)
#undef P1

    int nA = __builtin_amdgcn_readfirstlane(__shfl(numv, 0));
    int nB = __builtin_amdgcn_readfirstlane(__shfl(numv, 32));
    const bool skipA = (nA <= 16);
    const bool skipB = (nB <= 16);

#define S1(o) { x2s1[lane*33 + (o)] = splitbf(x1_##o); x2s1[lane*33 + 8 + (o)] = splitbf(m1_##o); }
    REP8_0(S1)
#undef S1

    bf16x8 BA[8], BB[8];
    {
        const uint4* bh3 = (const uint4*)w3fh + lane;
        const uint4* bl3 = (const uint4*)w3fl + lane;
        LDB8(BA, bh3, bl3)
    }

    f32x4 f2[8];
#pragma unroll
    for (int i = 0; i < 8; i++) f2[i] = (f32x4){0.f,0.f,0.f,0.f};
    {
        { bf16x8 Ah_,Al_; LDA2(x2s1,0,Ah_,Al_) MF3(f2[0],Ah_,Al_,Bw2[0],Bw2[1]) MF3(f2[1],Ah_,Al_,Bw2[2],Bw2[3]) }
        { bf16x8 Ah_,Al_; LDA2(x2s1,1,Ah_,Al_) MF3(f2[2],Ah_,Al_,Bw2[0],Bw2[1]) MF3(f2[3],Ah_,Al_,Bw2[2],Bw2[3]) }
        { bf16x8 Ah_,Al_; LDA2(x2s1,2,Ah_,Al_) MF3(f2[4],Ah_,Al_,Bw2[0],Bw2[1]) MF3(f2[5],Ah_,Al_,Bw2[2],Bw2[3]) }
        { bf16x8 Ah_,Al_; LDA2(x2s1,3,Ah_,Al_) MF3(f2[6],Ah_,Al_,Bw2[0],Bw2[1]) MF3(f2[7],Ah_,Al_,Bw2[2],Bw2[3]) }
    }

    {
        const uint4* bh3 = (const uint4*)w3fh + 256 + lane;
        const uint4* bl3 = (const uint4*)w3fl + 256 + lane;
        LDB8(BB, bh3, bl3)
    }

    float s2a = fold[16+c0], t2a = fold[48+c0];
    float s2b = fold[32+c0], t2b = fold[64+c0];
#define MSH4(s, SS, TT) { f2[s].x=mishf(f2[s].x*(SS)+(TT)); f2[s].y=mishf(f2[s].y*(SS)+(TT)); \
                          f2[s].z=mishf(f2[s].z*(SS)+(TT)); f2[s].w=mishf(f2[s].w*(SS)+(TT)); }
    MSH4(0,s2a,t2a) MSH4(1,s2b,t2b) MSH4(2,s2a,t2a) MSH4(3,s2b,t2b)
    MSH4(4,s2a,t2a) MSH4(5,s2b,t2b) MSH4(6,s2a,t2a) MSH4(7,s2b,t2b)
#undef MSH4

#define MX4(V) fmaxf(fmaxf((V).x,(V).y), fmaxf((V).z,(V).w))
    float aggA0 = fmaxf(MX4(f2[0]), MX4(f2[2]));
    float aggA1 = fmaxf(MX4(f2[1]), MX4(f2[3]));
    float aggB0 = fmaxf(MX4(f2[4]), MX4(f2[6]));
    float aggB1 = fmaxf(MX4(f2[5]), MX4(f2[7]));
#undef MX4
#define REDQ(p) p = fmaxf(p, __shfl_xor(p, 16)); p = fmaxf(p, __shfl_xor(p, 32));
    REDQ(aggA0) REDQ(aggA1) REDQ(aggB0) REDQ(aggB1)
#undef REDQ
    uint sgA0 = splitbf(aggA0), sgA1 = splitbf(aggA1);
    uint sgB0 = splitbf(aggB0), sgB1 = splitbf(aggB1);

#define ST2(mt, NVV, SG0, SG1) { \
    int rt_ = quad*4 + 16*((mt)&1); \
    int gr_ = (quad*4 + 16*(mt))*33; \
    float m0_=(rt_+0<(NVV))?1.f:0.f, m1_=(rt_+1<(NVV))?1.f:0.f; \
    float m2_=(rt_+2<(NVV))?1.f:0.f, m3_=(rt_+3<(NVV))?1.f:0.f; \
    f32x4 a_ = f2[(mt)*2], b_ = f2[(mt)*2+1]; \
    x2s[gr_    + c0] = splitbf(a_.x*m0_);  x2s[gr_    + c0+16] = splitbf(b_.x*m0_); \
    x2s[gr_+33 + c0] = splitbf(a_.y*m1_);  x2s[gr_+33 + c0+16] = splitbf(b_.y*m1_); \
    x2s[gr_+66 + c0] = splitbf(a_.z*m2_);  x2s[gr_+66 + c0+16] = splitbf(b_.z*m2_); \
    x2s[gr_+99 + c0] = splitbf(a_.w*m3_);  x2s[gr_+99 + c0+16] = splitbf(b_.w*m3_); \
    x2s1[gr_    + c0] = (m0_!=0.f)?(SG0):0u;  x2s1[gr_    + c0+16] = (m0_!=0.f)?(SG1):0u; \
    x2s1[gr_+33 + c0] = (m1_!=0.f)?(SG0):0u;  x2s1[gr_+33 + c0+16] = (m1_!=0.f)?(SG1):0u; \
    x2s1[gr_+66 + c0] = (m2_!=0.f)?(SG0):0u;  x2s1[gr_+66 + c0+16] = (m2_!=0.f)?(SG1):0u; \
    x2s1[gr_+99 + c0] = (m3_!=0.f)?(SG0):0u;  x2s1[gr_+99 + c0+16] = (m3_!=0.f)?(SG1):0u; }
    ST2(0, nA, sgA0, sgA1)
    ST2(2, nB, sgB0, sgB1)
    if (!skipA) { ST2(1, nA, sgA0, sgA1) }
    if (!skipB) { ST2(3, nB, sgB0, sgB1) }
#undef ST2

    f32x4 e[16];
#define EIN(i) e[i] = (f32x4){0.f,0.f,0.f,0.f};
    REP16_0(EIN)
#undef EIN
    DOSETA(x2s,  BA, e, skipA, skipB)
    DOSETA(x2s1, BB, e, skipA, skipB)

    {
        const uint4* bh4 = (const uint4*)w4fh + lane;
        const uint4* bl4 = (const uint4*)w4fl + lane;
        LDB8(BA, bh4, bl4)
    }

    uint* x3st = x2s1;
    f32x4 d[16];
#define DIN(i) d[i] = (f32x4){0.f,0.f,0.f,0.f};
    REP16_0(DIN)
#undef DIN

#define POST(TI, mt, nt) { \
    float s_ = fold[80 + c0 + 16*(nt)], tb_ = fold[144 + c0 + 16*(nt)]; \
    int col_ = c0 + 16*((nt)&1); \
    int rowb_ = quad*4 + 16*(mt); \
    x3st[(rowb_+0)*33 + col_] = splitbf(mishf(e[TI].x * s_ + tb_)); \
    x3st[(rowb_+1)*33 + col_] = splitbf(mishf(e[TI].y * s_ + tb_)); \
    x3st[(rowb_+2)*33 + col_] = splitbf(mishf(e[TI].z * s_ + tb_)); \
    x3st[(rowb_+3)*33 + col_] = splitbf(mishf(e[TI].w * s_ + tb_)); }

    {
        POST(0,0,0)  POST(1,0,1)
        POST(8,2,0)  POST(9,2,1)
        if (!skipA) { POST(4,1,0)  POST(5,1,1) }
        if (!skipB) { POST(12,3,0) POST(13,3,1) }
        DOSETA(x3st, BA, d, skipA, skipB)
    }
    {
        const uint4* bh4 = (const uint4*)w4fh + 256 + lane;
        const uint4* bl4 = (const uint4*)w4fl + 256 + lane;
        LDB8(BB, bh4, bl4)
    }
    {
        POST(2,0,2)  POST(3,0,3)
        POST(10,2,2) POST(11,2,3)
        if (!skipA) { POST(6,1,2)  POST(7,1,3) }
        if (!skipB) { POST(14,3,2) POST(15,3,3) }
        DOSETA(x3st, BB, d, skipA, skipB)
    }
#undef POST

    float s0f = fold[208+c0],    t0f = fold[272+c0];
    float s1f = fold[208+16+c0], t1f = fold[272+16+c0];
    float s2f = fold[208+32+c0], t2f = fold[272+32+c0];
    float s3f = fold[208+48+c0], t3f = fold[272+48+c0];
    float piA = skipA ? 0.f : -3.4e38f;
    float piB = skipB ? 0.f : -3.4e38f;
    float pA0=piA, pA1=piA, pA2=piA, pA3=piA;
    float pB0=piB, pB1=piB, pB2=piB, pB3=piB;

#define RECON(u) (__uint_as_float((u)<<16) + __uint_as_float((u) & 0xFFFF0000u))
#define FTP(D, mt, nt, SS, TT, PV) { \
    int nv = ((mt) >> 1) ? nB : nA; \
    int rf = quad*4 + 16*(mt); \
    int rt = quad*4 + 16*((mt)&1); \
    int cb = c0 + 16*(nt); \
    float m0=(rt+0<nv)?1.f:0.f, m1=(rt+1<nv)?1.f:0.f, m2=(rt+2<nv)?1.f:0.f, m3=(rt+3<nv)?1.f:0.f; \
    uint ua_ = x2s[(rf+0)*33 + cb], ub_ = x2s[(rf+1)*33 + cb]; \
    uint uc_ = x2s[(rf+2)*33 + cb], ud_ = x2s[(rf+3)*33 + cb]; \
    float y0 = mishf(D.x*SS + TT)*m0 + RECON(ua_); \
    float y1 = mishf(D.y*SS + TT)*m1 + RECON(ub_); \
    float y2 = mishf(D.z*SS + TT)*m2 + RECON(uc_); \
    float y3 = mishf(D.w*SS + TT)*m3 + RECON(ud_); \
    PV = fmaxf(PV, fmaxf(fmaxf(y0,y1), fmaxf(y2,y3))); }

#define FTA(D, mt, nt, SS, TT, AG, PV) { \
    int nv = ((mt) >> 1) ? nB : nA; \
    int rt = quad*4 + 16*((mt)&1); \
    float m0=(rt+0<nv)?1.f:0.f, m1=(rt+1<nv)?1.f:0.f, m2=(rt+2<nv)?1.f:0.f, m3=(rt+3<nv)?1.f:0.f; \
    float y0 = (mishf(D.x*SS + TT) + AG)*m0; \
    float y1 = (mishf(D.y*SS + TT) + AG)*m1; \
    float y2 = (mishf(D.z*SS + TT) + AG)*m2; \
    float y3 = (mishf(D.w*SS + TT) + AG)*m3; \
    PV = fmaxf(PV, fmaxf(fmaxf(y0,y1), fmaxf(y2,y3))); }

    FTP(d[0], 0, 0, s0f, t0f, pA0)  FTP(d[1], 0, 1, s1f, t1f, pA1)
    FTA(d[2], 0, 2, s2f, t2f, aggA0, pA2)  FTA(d[3], 0, 3, s3f, t3f, aggA1, pA3)
    if (!skipA) {
        FTP(d[4], 1, 0, s0f, t0f, pA0)  FTP(d[5], 1, 1, s1f, t1f, pA1)
        FTA(d[6], 1, 2, s2f, t2f, aggA0, pA2)  FTA(d[7], 1, 3, s3f, t3f, aggA1, pA3)
    }
    FTP(d[8], 2, 0, s0f, t0f, pB0)  FTP(d[9], 2, 1, s1f, t1f, pB1)
    FTA(d[10], 2, 2, s2f, t2f, aggB0, pB2)  FTA(d[11], 2, 3, s3f, t3f, aggB1, pB3)
    if (!skipB) {
        FTP(d[12], 3, 0, s0f, t0f, pB0)  FTP(d[13], 3, 1, s1f, t1f, pB1)
        FTA(d[14], 3, 2, s2f, t2f, aggB0, pB2)  FTA(d[15], 3, 3, s3f, t3f, aggB1, pB3)
    }
#undef FTP
#undef FTA
#undef RECON

#define RED(p) p = fmaxf(p, __shfl_xor(p, 16)); p = fmaxf(p, __shfl_xor(p, 32));
    RED(pA0) RED(pA1) RED(pA2) RED(pA3) RED(pB0) RED(pB1) RED(pB2) RED(pB3)
#undef RED

    if (quad == 0) {
        float* vwA = voxelwise + vA*64;
        vwA[c0] = pA0; vwA[c0+16] = pA1; vwA[c0+32] = pA2; vwA[c0+48] = pA3;
        float* vwB = voxelwise + (vA+1)*64;
        vwB[c0] = pB0; vwB[c0+16] = pB1; vwB[c0+32] = pB2; vwB[c0+48] = pB3;
    }

    if (t == 0) {
        int cell = coors[v*2] * BEVW + coors[v*2+1];
        int pos = atomicAdd(&cnt[cell], 1);
        if (pos < 16) list[cell*16 + pos] = v;
        if (pos == 0) { int k = atomicAdd(nact, 1); act[k] = cell; }
    }
}

// ---------------- bfe_back: fused bfe_front + bfe3 (MFMA), x19 into x17g ----------------
// (unchanged from round 7)
__global__ __launch_bounds__(512) void bfe_back(
    const int* __restrict__ nactp, const int* __restrict__ act,
    const int* __restrict__ cnt, const int* __restrict__ list,
    const float* __restrict__ voxelwise,
    const float* __restrict__ W1g, const float* __restrict__ W2g,
    const float* __restrict__ W3, const float* __restrict__ fold,
    float* __restrict__ x17g, int* __restrict__ idx)
{
    __shared__ uint XA[4*2112];   // 4 K-chunks of [64 rows][33] split-u32 (33792 B)
    int tid = threadIdx.x;
    int n_act = *nactp;
    int cb = blockIdx.x * 64;
    int wv = tid >> 6;
    int lane = tid & 63;
    int quad = lane >> 4, c0 = lane & 15;
    int g = lane >> 2, ii = lane & 3;

    // ---- phase 1: bfe_front for 8 cells per wave; x17 split-bf16 -> LDS ----
    for (int r = 0; r < 8; r++) {
        int ci = (wv << 3) + r;
        int aidx = cb + ci;
        uint z0u = 0u, z1u = 0u;
        if (aidx < n_act) {
            int cell = act[aidx];
            int numv = min(cnt[cell], 16);
            if (lane == 0) idx[cell] = aidx + 1;
            int myidx = (lane < numv) ? list[cell*16 + lane] : (0x40000000 + lane);
            int rank = 0;
            for (int j = 0; j < numv; j++) { int vj = __shfl(myidx, j); rank += (vj < myidx) ? 1 : 0; }
            if (lane >= numv) rank = lane;
            int sorted = __builtin_amdgcn_ds_permute(rank << 2, myidx);

#define YD(q) float y_##q = 0.f;
            REP16_0(YD)
#undef YD
            for (int p = 0; p < numv; p++) {
                int sv = __shfl(sorted, p);
                float val = voxelwise[sv*64 + lane];
                const float* w = W1g + g*256 + p;
#define BF1(q) y_##q += val * w[(q)*16];
                REP16_0(BF1)
#undef BF1
            }
#define BN1(q) { float yy = y_##q * fold[592 + g*16 + (q)] + fold[848 + g*16 + (q)]; \
    yy = mishf(yy); y_##q = ((q) < numv) ? yy : 0.f; }
            REP16_0(BN1)
#undef BN1
            float z0 = 0.f, z1 = 0.f;
#define BF2(p) z0 += y_##p * W2g[g*32 + (p)]; z1 += y_##p * W2g[g*32 + 16 + (p)];
            REP16_0(BF2)
#undef BF2
            z0 = mishf(z0 * fold[1104 + g*2 + 0] + fold[1136 + g*2 + 0]);
            z1 = mishf(z1 * fold[1104 + g*2 + 1] + fold[1136 + g*2 + 1]);
            z0u = splitbf(z0); z1u = splitbf(z1);
        }
        // x17 col k0 = ii*32 + g*2 -> chunk ii, col g*2 (and +1)
        XA[ii*2112 + ci*33 + g*2]     = z0u;
        XA[ii*2112 + ci*33 + g*2 + 1] = z1u;
    }
    __syncthreads();

    // ---- B fragments for bfe3_W: wave wv owns channels nch = c0 + 16*wv ----
    int nch = c0 + (wv << 4);
    float s5 = fold[336 + nch], t5 = fold[464 + nch];
#define BLD(KC) bf16x8 B3h##KC, B3l##KC; { \
    const float* wr = W3 + nch*128 + (KC)*32 + quad*8; \
    float4 wa = *(const float4*)wr; float4 wb = *(const float4*)(wr+4); \
    uint u0=splitbf(wa.x), u1=splitbf(wa.y), u2=splitbf(wa.z), u3=splitbf(wa.w); \
    uint u4=splitbf(wb.x), u5=splitbf(wb.y), u6=splitbf(wb.z), u7=splitbf(wb.w); \
    B3h##KC = mkbf8(__builtin_amdgcn_perm(u1,u0,0x05040100), __builtin_amdgcn_perm(u3,u2,0x05040100), \
                    __builtin_amdgcn_perm(u5,u4,0x05040100), __builtin_amdgcn_perm(u7,u6,0x05040100)); \
    B3l##KC = mkbf8(__builtin_amdgcn_perm(u1,u0,0x07060302), __builtin_amdgcn_perm(u3,u2,0x07060302), \
                    __builtin_amdgcn_perm(u5,u4,0x07060302), __builtin_amdgcn_perm(u7,u6,0x07060302)); }
    BLD(0) BLD(1) BLD(2) BLD(3)
#undef BLD

#define KSTEP(KC, Q0, Q1, Q2, Q3) { \
    const uint* ch_ = XA + (KC)*2112; \
    bf16x8 Ah0,Al0,Ah1,Al1,Ah2,Al2,Ah3,Al3; \
    LDA(ch_,0,Ah0,Al0) LDA(ch_,1,Ah1,Al1) LDA(ch_,2,Ah2,Al2) LDA(ch_,3,Ah3,Al3) \
    MF3(Q0,Ah0,Al0,B3h##KC,B3l##KC) MF3(Q1,Ah1,Al1,B3h##KC,B3l##KC) \
    MF3(Q2,Ah2,Al2,B3h##KC,B3l##KC) MF3(Q3,Ah3,Al3,B3h##KC,B3l##KC) }

#define PASS3(Q0,Q1,Q2,Q3) \
    Q0 = (f32x4){0.f,0.f,0.f,0.f}; Q1 = Q0; Q2 = Q0; Q3 = Q0; \
    KSTEP(0,Q0,Q1,Q2,Q3) KSTEP(1,Q0,Q1,Q2,Q3) KSTEP(2,Q0,Q1,Q2,Q3) KSTEP(3,Q0,Q1,Q2,Q3)

#define ACT4(Q) { Q.x = mishf(Q.x*s5+t5); Q.y = mishf(Q.y*s5+t5); \
                  Q.z = mishf(Q.z*s5+t5); Q.w = mishf(Q.w*s5+t5); }

    // ---- pass 1 (x18 = fe(x17)) ----
    f32x4 q0, q1, q2, q3;
    PASS3(q0,q1,q2,q3)
    ACT4(q0) ACT4(q1) ACT4(q2) ACT4(q3)
    __syncthreads();   // all waves done reading XA before overwrite
    {
        uint* dst = XA + (wv >> 1)*2112 + ((wv & 1) << 4) + c0;
        int rb = quad*4;
        dst[(rb+0)*33]      = splitbf(q0.x); dst[(rb+1)*33]      = splitbf(q0.y);
        dst[(rb+2)*33]      = splitbf(q0.z); dst[(rb+3)*33]      = splitbf(q0.w);
        dst[(rb+16)*33]     = splitbf(q1.x); dst[(rb+17)*33]     = splitbf(q1.y);
        dst[(rb+18)*33]     = splitbf(q1.z); dst[(rb+19)*33]     = splitbf(q1.w);
        dst[(rb+32)*33]     = splitbf(q2.x); dst[(rb+33)*33]     = splitbf(q2.y);
        dst[(rb+34)*33]     = splitbf(q2.z); dst[(rb+35)*33]     = splitbf(q2.w);
        dst[(rb+48)*33]     = splitbf(q3.x); dst[(rb+49)*33]     = splitbf(q3.y);
        dst[(rb+50)*33]     = splitbf(q3.z); dst[(rb+51)*33]     = splitbf(q3.w);
    }
    __syncthreads();

    // ---- pass 2 (x19 = fe(x18)), same W/bn ----
    PASS3(q0,q1,q2,q3)
    ACT4(q0) ACT4(q1) ACT4(q2) ACT4(q3)
#undef ACT4
#undef PASS3
#undef KSTEP

    // store x19 fp32 to x17g[cell][128]
    {
        size_t rb = (size_t)(cb + quad*4);
        x17g[(rb+0)*128 + nch] = q0.x;  x17g[(rb+1)*128 + nch] = q0.y;
        x17g[(rb+2)*128 + nch] = q0.z;  x17g[(rb+3)*128 + nch] = q0.w;
        x17g[(rb+16)*128 + nch] = q1.x; x17g[(rb+17)*128 + nch] = q1.y;
        x17g[(rb+18)*128 + nch] = q1.z; x17g[(rb+19)*128 + nch] = q1.w;
        x17g[(rb+32)*128 + nch] = q2.x; x17g[(rb+33)*128 + nch] = q2.y;
        x17g[(rb+34)*128 + nch] = q2.z; x17g[(rb+35)*128 + nch] = q2.w;
        x17g[(rb+48)*128 + nch] = q3.x; x17g[(rb+49)*128 + nch] = q3.y;
        x17g[(rb+50)*128 + nch] = q3.z; x17g[(rb+51)*128 + nch] = q3.w;
    }
}

// ---------------- bev_write: tiled transpose-scatter (replaces out memset) ----------------
__global__ __launch_bounds__(512, 2) void bev_write(
    const int* __restrict__ idx, const float* __restrict__ x19c,
    float* __restrict__ out)
{
    __shared__ float XT[128*65];
    int bid = blockIdx.x;
    int cx = bid % BEVW;
    int cy0 = (bid / BEVW) << 6;
    int tid = threadIdx.x;

    int cell_l = tid >> 3;
    int chq = (tid & 7) << 4;
    int cy = cy0 + cell_l;
    float4 v0 = make_float4(0.f,0.f,0.f,0.f), v1 = v0, v2 = v0, v3 = v0;
    if (cy < BEVH) {
        int ai = idx[cy*BEVW + cx] - 1;
        if (ai >= 0) {
            const float4* src = (const float4*)(x19c + (size_t)ai*128 + chq);
            v0 = src[0]; v1 = src[1]; v2 = src[2]; v3 = src[3];
        }
    }
    float* d = XT + chq*65 + cell_l;
    d[0*65]=v0.x;  d[1*65]=v0.y;  d[2*65]=v0.z;  d[3*65]=v0.w;
    d[4*65]=v1.x;  d[5*65]=v1.y;  d[6*65]=v1.z;  d[7*65]=v1.w;
    d[8*65]=v2.x;  d[9*65]=v2.y;  d[10*65]=v2.z; d[11*65]=v2.w;
    d[12*65]=v3.x; d[13*65]=v3.y; d[14*65]=v3.z; d[15*65]=v3.w;
    __syncthreads();

    int wv2 = tid >> 6, lane = tid & 63;
    int cyw = cy0 + lane;
    if (cyw < BEVH) {
        float* op = out + cx*BEVH + cyw;
#pragma unroll
        for (int k = 0; k < 16; k++) {
            int c = (wv2 << 4) + k;
            op[(size_t)c*NCELL] = XT[c*65 + lane];
        }
    }
}

extern "C" void kernel_launch(void* const* d_in, const int* in_sizes, int n_in,
                              void* d_out, int out_size, void* d_ws, size_t ws_size,
                              hipStream_t stream) {
    const float* features = (const float*)d_in[0];
    const int*   coors    = (const int*)d_in[1];
    const int*   num_vox  = (const int*)d_in[2];
    const float* vfe1_W   = (const float*)d_in[3];
    const float* vfe1_bn  = (const float*)d_in[4];
    const float* vfe2_W   = (const float*)d_in[5];
    const float* vfe2_bn  = (const float*)d_in[6];
    const float* vfe3_W   = (const float*)d_in[7];
    const float* vfe3_bn  = (const float*)d_in[8];
    const float* vfe4_W   = (const float*)d_in[9];
    const float* vfe4_bn  = (const float*)d_in[10];
    const float* bfe1_W   = (const float*)d_in[11];
    const float* bfe1_bn  = (const float*)d_in[12];
    const float* bfe2_W   = (const float*)d_in[13];
    const float* bfe2_bn  = (const float*)d_in[14];
    const float* bfe3_W   = (const float*)d_in[15];
    const float* bfe3_bn  = (const float*)d_in[16];
    float* out = (float*)d_out;

    char* ws = (char*)d_ws;
    int*    nact      = (int*)ws;                       // zeroed by setup
    int*    cnt       = (int*)(ws + 256);               // zeroed by setup
    int*    idx       = (int*)(ws + 857344);            // zeroed by setup (aidx+1 encoding)
    int*    list      = (int*)(ws + 1714432);
    float*  voxelwise = (float*)(ws + 15427840);
    int*    act       = (int*)(ws + 25667840);
    float*  x17g      = (float*)(ws + 25827840);
    float*  fold      = (float*)(ws + 46307840);
    ushort* w4fh      = (ushort*)(ws + 46312512);
    ushort* w4fl      = (ushort*)(ws + 46320704);
    ushort* w3fh      = (ushort*)(ws + 46328896);
    ushort* w3fl      = (ushort*)(ws + 46337088);
    ushort* w2fh      = (ushort*)(ws + 46345280);
    ushort* w2fl      = (ushort*)(ws + 46347328);

    setup_kernel<<<48, 256, 0, stream>>>(vfe1_bn, vfe2_bn, vfe3_bn, vfe4_bn,
                                         bfe1_bn, bfe2_bn, bfe3_bn, vfe4_W, vfe3_W, vfe2_W,
                                         fold, w4fh, w4fl, w3fh, w3fl, w2fh, w2fl,
                                         (uint4*)ws);
    vfe_kernel<<<NVOX/2, 64, 0, stream>>>(features, coors, num_vox,
                                          vfe1_W, w2fh, w2fl, w3fh, w3fl, w4fh, w4fl, fold,
                                          voxelwise, cnt, list, nact, act);
    bfe_back<<<(NVOX+63)/64, 512, 0, stream>>>(nact, act, cnt, list, voxelwise,
                                               bfe1_W, bfe2_W, bfe3_W, fold, x17g, idx);
    bev_write<<<BEVW*8, 512, 0, stream>>>(idx, x17g, out);
}